// Round 4
// baseline (891.476 us; speedup 1.0000x reference)
//
#include <hip/hip_runtime.h>
#include <hip/hip_bf16.h>
#include <math.h>

// x:[2,256,256,512] f32 -> out:[2,256,128,256] f32
// Planes p = 2m (Re), 2m+1 (Im), m=0..127 (m=128 slice of wmat_hi is identically 0).

#define ROWS_HI 131072   // B*C*H_HI
#define ROWS_LO 65536    // B*C*H_LO

// ws byte offsets
#define B_FT    0LL           // F_T  bf16 [256 p][512 w]
#define B_FIT   262144LL      // Fi_T bf16 [256 w'][256 p]
#define B_WM    393216LL      // wmat bf16 [128 m][128 l][256 k]
#define B_PCT   8781824LL     // pctT bf16 [128 m][128 k'][128 l]
#define B_WB    12976128LL    // conv_w bf16 [256 o][256 c]
#define B_STATS 13107200LL    // 128 floats
#define B_R1    13107712LL    // 64 MB region: Xbf(64MB) -> gb(32MB) -> ybf(32MB)
#define B_R2    80216576LL    // 32 MB region: flmb -> gTb -> yT (all bf16)

typedef __attribute__((ext_vector_type(8))) short bf16x8;
typedef __attribute__((ext_vector_type(8))) unsigned short ushort8;
typedef __attribute__((ext_vector_type(4))) unsigned short ushort4v;
typedef __attribute__((ext_vector_type(4))) float f32x4;

__device__ inline unsigned short f2bf(float f){
  unsigned int u = __float_as_uint(f);
  unsigned int r = u + 0x7FFFu + ((u >> 16) & 1u);
  return (unsigned short)(r >> 16);
}
__device__ inline unsigned int pk2bf(float a, float b){
  // packed RNE f32->bf16 pair (v_cvt_pk_bf16_f32 on gfx950)
  unsigned int lo = (unsigned int)f2bf(a);
  unsigned int hi = (unsigned int)f2bf(b);
  return lo | (hi << 16);
}

// ---------------- tables: DFT/iDFT twiddles (bf16) + zero stats ---------------
__global__ __launch_bounds__(256) void k_tables(unsigned char* __restrict__ ws){
  unsigned short* FT  = (unsigned short*)(ws + B_FT);
  unsigned short* FIT = (unsigned short*)(ws + B_FIT);
  float* stats = (float*)(ws + B_STATS);
  int idx = blockIdx.x*256 + threadIdx.x;
  if (idx < 131072){            // F_T[p][w]
    int p = idx >> 9, w = idx & 511, m = p >> 1;
    int pr = (m*w) & 511;
    float ang = (float)pr * (float)(2.0*M_PI/512.0);
    float s, c; sincosf(ang, &s, &c);
    const float S = (float)(2.0*M_PI/512.0);
    FT[idx] = f2bf((p & 1) ? (-S*s) : (S*c));
  }
  int i2 = idx - 131072;
  if (i2 >= 0 && i2 < 65536){   // Fi_T[w'][p]
    int w = i2 >> 8, p = i2 & 255, m = p >> 1;
    float eps = (m == 0) ? 1.f : 2.f;
    int pr = (m*w) & 255;
    float ang = (float)pr * (float)(2.0*M_PI/256.0);
    float s, c; sincosf(ang, &s, &c);
    FIT[i2] = f2bf((p & 1) ? (-eps*s) : (eps*c));
  }
  int i3 = idx - (131072 + 65536);
  if (i3 >= 0 && i3 < 128) stats[i3] = 0.f;
}

// ------- prep: wmat->bf16, pct->bf16 transposed, conv_w->bf16 ----------------
__global__ __launch_bounds__(256) void k_prep(const float* __restrict__ wmat,
                                              const float* __restrict__ pct,
                                              const float* __restrict__ Wc,
                                              unsigned char* __restrict__ ws){
  unsigned short* WM = (unsigned short*)(ws + B_WM);
  unsigned short* PT = (unsigned short*)(ws + B_PCT);
  unsigned short* WB = (unsigned short*)(ws + B_WB);
  int idx = blockIdx.x*256 + threadIdx.x;
  if (idx < 4194304){
    WM[idx] = f2bf(wmat[idx]);            // [m][l][k] direct, m<128
  } else if (idx < 6291456){
    int j = idx - 4194304;                // pctT[m][kp][l] = pct[m][l][kp]
    int m = j >> 14, kp = (j >> 7) & 127, l = j & 127;
    PT[j] = f2bf(pct[m*16384 + l*128 + kp]);
  } else if (idx < 6356992){
    int j = idx - 6291456;
    WB[j] = f2bf(Wc[j]);                  // [o][c]
  }
}

// ---------------- MFMA GEMM: BM=BN=128, BK=64, MT=NT=4 ------------------------
// C[M][N] = A[M][K] * B_T[N][K]^T ; 256 thr = 2x2 waves, wave = 64x64 tile.
// AMODE 0: A fp32 -> bf16 quantize in staging ; AMODE 1: A bf16
// CMODE 0: row-major fp32 (+bias[row], + optional fused GN-stats atomics)
// CMODE 1: transposed bf16 C_T[col][row] ; CMODE 2: row-major bf16
// SKIP 1: skip nt-tiles fully l<m (leg1) ; SKIP 2: k-loop starts at m>>6 (leg2)
template<int AMODE, int CMODE, bool BIAS, int SKIP, bool STATS>
__global__ __launch_bounds__(256, 3) void k_gemm(
    const float* __restrict__ Af,
    const unsigned short* __restrict__ Abf,
    const unsigned short* __restrict__ Bt,
    float* __restrict__ Cf,
    unsigned short* __restrict__ Cbf,
    const float* __restrict__ bias,
    float* __restrict__ stats,
    int ldA, int ldB, int ldC, int ksteps,
    long long sA, long long sB, int bzsh, long long sC)
{
  __shared__ unsigned short As[128][80];
  __shared__ unsigned short Bs[128][80];
  const int tid = threadIdx.x;
  const int z = blockIdx.z;
  const int m = z >> 1;
  const long long offA = (long long)z * sA;
  const long long offB = (long long)(z >> bzsh) * sB;
  const long long offC = (long long)z * sC;
  const int row0 = blockIdx.x * 128;
  const int n0   = blockIdx.y * 128;
  const int lane = tid & 63;
  const int wv = tid >> 6;
  const int wm = wv >> 1, wn = wv & 1;
  const int fr = lane & 15, q = lane >> 4;
  const int srow = tid >> 1, shalf = tid & 1;   // staging: 2 threads/row, 32 k each

  f32x4 acc[4][4];
#pragma unroll
  for (int i=0;i<4;++i)
#pragma unroll
    for (int j=0;j<4;++j) acc[i][j] = (f32x4){0.f,0.f,0.f,0.f};

  const int ks0 = (SKIP == 2) ? (m >> 6) : 0;
  for (int ks = ks0; ks < ksteps; ++ks){
    const int k0 = ks * 64;
    // ---- stage A (128 rows x 64 k)
    if (AMODE == 0){
      const float* s = Af + offA + (long long)(row0 + srow) * ldA + k0 + shalf*32;
#pragma unroll
      for (int b2=0;b2<2;++b2){
        float4 v0 = *(const float4*)(s + b2*16 + 0);
        float4 v1 = *(const float4*)(s + b2*16 + 4);
        float4 v2 = *(const float4*)(s + b2*16 + 8);
        float4 v3 = *(const float4*)(s + b2*16 + 12);
        unsigned int u0 = pk2bf(v0.x, v0.y), u1 = pk2bf(v0.z, v0.w);
        unsigned int u2 = pk2bf(v1.x, v1.y), u3 = pk2bf(v1.z, v1.w);
        unsigned int u4 = pk2bf(v2.x, v2.y), u5 = pk2bf(v2.z, v2.w);
        unsigned int u6 = pk2bf(v3.x, v3.y), u7 = pk2bf(v3.z, v3.w);
        unsigned int* d = (unsigned int*)&As[srow][shalf*32 + b2*16];
        d[0]=u0; d[1]=u1; d[2]=u2; d[3]=u3; d[4]=u4; d[5]=u5; d[6]=u6; d[7]=u7;
      }
    } else {
      const unsigned short* s = Abf + offA + (long long)(row0 + srow) * ldA + k0 + shalf*32;
      *(ushort8*)&As[srow][shalf*32]    = *(const ushort8*)(s);
      *(ushort8*)&As[srow][shalf*32+8]  = *(const ushort8*)(s+8);
      *(ushort8*)&As[srow][shalf*32+16] = *(const ushort8*)(s+16);
      *(ushort8*)&As[srow][shalf*32+24] = *(const ushort8*)(s+24);
    }
    // ---- stage B (128 rows x 64 k)
    {
      const unsigned short* s = Bt + offB + (long long)(n0 + srow) * ldB + k0 + shalf*32;
      *(ushort8*)&Bs[srow][shalf*32]    = *(const ushort8*)(s);
      *(ushort8*)&Bs[srow][shalf*32+8]  = *(const ushort8*)(s+8);
      *(ushort8*)&Bs[srow][shalf*32+16] = *(const ushort8*)(s+16);
      *(ushort8*)&Bs[srow][shalf*32+24] = *(const ushort8*)(s+24);
    }
    __syncthreads();
#pragma unroll
    for (int c=0;c<2;++c){
      bf16x8 ah[4];
#pragma unroll
      for (int mt=0;mt<4;++mt)
        ah[mt] = *(const bf16x8*)&As[wm*64+mt*16+fr][c*32 + q*8];
#pragma unroll
      for (int nt=0;nt<4;++nt){
        if (SKIP == 1 && (wn*64 + nt*16 + 16 <= m)) continue;
        bf16x8 bb = *(const bf16x8*)&Bs[wn*64+nt*16+fr][c*32 + q*8];
#pragma unroll
        for (int mt=0;mt<4;++mt)
          acc[mt][nt] = __builtin_amdgcn_mfma_f32_16x16x32_bf16(ah[mt], bb, acc[mt][nt], 0,0,0);
      }
    }
    __syncthreads();
  }

  if (CMODE == 0){
#pragma unroll
    for (int mt=0;mt<4;++mt){
      int row = row0 + wm*64 + mt*16 + q*4;
      float bv0=0.f,bv1=0.f,bv2=0.f,bv3=0.f;
      if (BIAS){ bv0=bias[row]; bv1=bias[row+1]; bv2=bias[row+2]; bv3=bias[row+3]; }
      float s_ = 0.f, ss_ = 0.f;
#pragma unroll
      for (int nt=0;nt<4;++nt){
        int col = n0 + wn*64 + nt*16 + fr;
        float* dst = Cf + offC + (long long)row * ldC + col;
        float v0 = acc[mt][nt][0] + bv0;
        float v1 = acc[mt][nt][1] + bv1;
        float v2 = acc[mt][nt][2] + bv2;
        float v3 = acc[mt][nt][3] + bv3;
        dst[0]                = v0;
        dst[(long long)ldC]   = v1;
        dst[(long long)ldC*2] = v2;
        dst[(long long)ldC*3] = v3;
        if (STATS){
          s_  += v0 + v1 + v2 + v3;
          ss_ += v0*v0 + v1*v1 + v2*v2 + v3*v3;
        }
      }
      if (STATS){
        // rows of this mt span 2 GN groups (8 rows each): q<2 -> gb, q>=2 -> gb+1
        float sl = (q < 2) ? s_ : 0.f, sh = (q < 2) ? 0.f : s_;
        float ql = (q < 2) ? ss_ : 0.f, qh = (q < 2) ? 0.f : ss_;
#pragma unroll
        for (int off=32; off>0; off>>=1){
          sl += __shfl_down(sl, off, 64);
          sh += __shfl_down(sh, off, 64);
          ql += __shfl_down(ql, off, 64);
          qh += __shfl_down(qh, off, 64);
        }
        if (lane == 0){
          int gb = (row0 + wm*64 + mt*16) >> 3;      // group index 0..31
          int bg0 = z*32 + gb;
          atomicAdd(&stats[bg0*2+0], sl);
          atomicAdd(&stats[bg0*2+1], ql);
          atomicAdd(&stats[(bg0+1)*2+0], sh);
          atomicAdd(&stats[(bg0+1)*2+1], qh);
        }
      }
    }
  } else if (CMODE == 1){
#pragma unroll
    for (int nt=0;nt<4;++nt){
      int colp = n0 + wn*64 + nt*16 + fr;
#pragma unroll
      for (int mt=0;mt<4;++mt){
        int rowb = row0 + wm*64 + mt*16 + q*4;
        unsigned int u0 = pk2bf(acc[mt][nt][0], acc[mt][nt][1]);
        unsigned int u1 = pk2bf(acc[mt][nt][2], acc[mt][nt][3]);
        unsigned int* d = (unsigned int*)&Cbf[offC + (long long)colp * ldC + rowb];
        d[0] = u0; d[1] = u1;
      }
    }
  } else {
#pragma unroll
    for (int mt=0;mt<4;++mt){
      int row = row0 + wm*64 + mt*16 + q*4;
#pragma unroll
      for (int nt=0;nt<4;++nt){
        int col = n0 + wn*64 + nt*16 + fr;
        unsigned short* dst = Cbf + offC + (long long)row * ldC + col;
        dst[0]      = f2bf(acc[mt][nt][0]);
        dst[ldC]    = f2bf(acc[mt][nt][1]);
        dst[ldC*2]  = f2bf(acc[mt][nt][2]);
        dst[ldC*3]  = f2bf(acc[mt][nt][3]);
      }
    }
  }
}

// ------- transpose bf16 g[256 p][65536 r] -> gT[65536 r][256 p] ---------------
__global__ __launch_bounds__(256) void k_trb(const unsigned short* __restrict__ g,
                                             unsigned short* __restrict__ gT){
  __shared__ unsigned short t[64][68];
  const int r0 = blockIdx.x * 64;
  const int p0 = blockIdx.y * 64;
  const int tr = threadIdx.x & 15, tc = threadIdx.x >> 4;
#pragma unroll
  for (int i=0;i<4;++i){
    int pl = tc + i*16;
    ushort4v v = *(const ushort4v*)(g + (long long)(p0+pl)*ROWS_LO + r0 + tr*4);
    *(ushort4v*)&t[pl][tr*4] = v;
  }
  __syncthreads();
#pragma unroll
  for (int i=0;i<4;++i){
    int rl = tc + i*16;
    ushort4v w;
    w[0]=t[tr*4+0][rl]; w[1]=t[tr*4+1][rl]; w[2]=t[tr*4+2][rl]; w[3]=t[tr*4+3][rl];
    *(ushort4v*)(gT + (long long)(r0+rl)*256 + p0 + tr*4) = w;
  }
}

// ------- transpose y[b][256 c][32768 s] bf16 -> yT[b][s][c] bf16 --------------
__global__ __launch_bounds__(256) void k_tr2b(const unsigned short* __restrict__ y,
                                              unsigned short* __restrict__ yT){
  __shared__ unsigned short t[64][68];
  const int s0 = blockIdx.x * 64;
  const int c0 = blockIdx.y * 64;
  const int b  = blockIdx.z;
  const int tr = threadIdx.x & 15, tc = threadIdx.x >> 4;
#pragma unroll
  for (int i=0;i<4;++i){
    int cl = tc + i*16;
    ushort4v v = *(const ushort4v*)(y + (long long)b*8388608 + (long long)(c0+cl)*32768 + s0 + tr*4);
    *(ushort4v*)&t[cl][tr*4] = v;
  }
  __syncthreads();
#pragma unroll
  for (int i=0;i<4;++i){
    int sl = tc + i*16;
    ushort4v w;
    w[0]=t[tr*4+0][sl]; w[1]=t[tr*4+1][sl]; w[2]=t[tr*4+2][sl]; w[3]=t[tr*4+3][sl];
    *(ushort4v*)(yT + (long long)b*8388608 + (long long)(s0+sl)*256 + c0 + tr*4) = w;
  }
}

// ---------------- normalize + affine + exact GELU ----------------------------
__global__ __launch_bounds__(256) void k_norm(float* __restrict__ out,
                                              const float* __restrict__ stats,
                                              const float* __restrict__ gamma,
                                              const float* __restrict__ beta){
  long long idx4 = ((long long)blockIdx.x*256 + threadIdx.x)*4;
  int o = (int)((idx4 >> 15) & 255);
  int b = (int)(idx4 >> 23);
  int bg = b*32 + (o >> 3);
  const float inv_n = 1.0f/262144.0f;
  float mean = stats[bg*2+0] * inv_n;
  float var  = stats[bg*2+1] * inv_n - mean*mean;
  float sc = rsqrtf(var + 1e-5f);
  float ga = gamma[o], be = beta[o];
  float4 v = *(float4*)(out + idx4);
  float t0 = (v.x - mean)*sc*ga + be;
  float t1 = (v.y - mean)*sc*ga + be;
  float t2 = (v.z - mean)*sc*ga + be;
  float t3 = (v.w - mean)*sc*ga + be;
  const float ISQ2 = 0.70710678118654752f;
  v.x = 0.5f*t0*(1.0f + erff(t0*ISQ2));
  v.y = 0.5f*t1*(1.0f + erff(t1*ISQ2));
  v.z = 0.5f*t2*(1.0f + erff(t2*ISQ2));
  v.w = 0.5f*t3*(1.0f + erff(t3*ISQ2));
  *(float4*)(out + idx4) = v;
}

extern "C" void kernel_launch(void* const* d_in, const int* in_sizes, int n_in,
                              void* d_out, int out_size, void* d_ws, size_t ws_size,
                              hipStream_t stream){
  const float* x      = (const float*)d_in[0];
  const float* conv_w = (const float*)d_in[1];
  const float* conv_b = (const float*)d_in[2];
  const float* gamma  = (const float*)d_in[3];
  const float* beta   = (const float*)d_in[4];
  const float* wmat   = (const float*)d_in[5];
  const float* pct    = (const float*)d_in[6];
  unsigned char* ws = (unsigned char*)d_ws;

  unsigned short* FT   = (unsigned short*)(ws + B_FT);
  unsigned short* FIT  = (unsigned short*)(ws + B_FIT);
  unsigned short* WM   = (unsigned short*)(ws + B_WM);
  unsigned short* PT   = (unsigned short*)(ws + B_PCT);
  unsigned short* WB   = (unsigned short*)(ws + B_WB);
  float*          stats= (float*)(ws + B_STATS);
  unsigned short* Xbf  = (unsigned short*)(ws + B_R1);  // [256 p][131072] bf16
  unsigned short* gb   = (unsigned short*)(ws + B_R1);  // [256 p][65536] bf16 (Xbf dead)
  unsigned short* ybf  = (unsigned short*)(ws + B_R1);  // [65536 r][256 w'] bf16 (gb dead)
  unsigned short* flmb = (unsigned short*)(ws + B_R2);  // [256 p][512 bc][128 l] bf16
  unsigned short* gTb  = (unsigned short*)(ws + B_R2);  // [65536][256 p] bf16 (flmb dead)
  unsigned short* yT   = (unsigned short*)(ws + B_R2);  // [b][32768 s][256 c] bf16 (gTb dead)
  float* out = (float*)d_out;

  k_tables<<<769, 256, 0, stream>>>(ws);
  k_prep  <<<24832, 256, 0, stream>>>(wmat, pct, conv_w, ws);

  // DFT: A=x f32 [131072x512] (quantized in staging), B=F_T, C->Xbf trans bf16
  k_gemm<0,1,false,0,false><<<dim3(1024,2,1), 256, 0, stream>>>(
      x, nullptr, FT, nullptr, Xbf, nullptr, nullptr, 512, 512, ROWS_HI, 8, 0, 0, 0, 0);
  // Leg1: per plane: A=Xbf[p] [512x256], B=WM[m] [128l x256k], C=flmb bf16; skip l<m tiles
  k_gemm<1,2,false,1,false><<<dim3(4,1,256), 256, 0, stream>>>(
      nullptr, Xbf, WM, nullptr, flmb, nullptr, nullptr, 256, 256, 128, 4,
      131072LL, 32768LL, 1, 65536LL);
  // Leg2: per plane: A=flmb[p] [512x128], B=PT[m] [128k' x128l], C=gb bf16; k-start m>>6
  k_gemm<1,2,false,2,false><<<dim3(4,1,256), 256, 0, stream>>>(
      nullptr, flmb, PT, nullptr, gb, nullptr, nullptr, 128, 128, 128, 2,
      65536LL, 16384LL, 1, 65536LL);
  // transpose gb -> gTb
  k_trb<<<dim3(1024,4), 256, 0, stream>>>(gb, gTb);
  // iDFT: A=gTb [65536x256], B=Fi_T [256w' x256p], C=ybf bf16 row-major
  k_gemm<1,2,false,0,false><<<dim3(512,2,1), 256, 0, stream>>>(
      nullptr, gTb, FIT, nullptr, ybf, nullptr, nullptr, 256, 256, 256, 4, 0, 0, 0, 0);
  // transpose ybf -> yT
  k_tr2b<<<dim3(512,4,2), 256, 0, stream>>>(ybf, yT);
  // Conv: per b: A=WB [256x256], B=yT[b] [32768x256], C=out f32 +bias, fused GN stats
  k_gemm<1,0,true,0,true><<<dim3(2,256,2), 256, 0, stream>>>(
      nullptr, WB, yT, out, nullptr, conv_b, stats, 256, 256, 32768, 4,
      0, 8388608LL, 0, 8388608LL);

  k_norm <<<16384, 256, 0, stream>>>(out, stats, gamma, beta);
}